// Round 1
// baseline (512.781 us; speedup 1.0000x reference)
//
#include <hip/hip_runtime.h>
#include <stdint.h>

typedef unsigned short u16;
typedef __attribute__((ext_vector_type(8))) short frag8;   // 8 bf16 in 4 VGPRs
typedef __attribute__((ext_vector_type(4))) float f32x4;
typedef __attribute__((ext_vector_type(4))) unsigned short u16x4;

#define MFMA_BF16(a,b,c) __builtin_amdgcn_mfma_f32_16x16x32_bf16((a),(b),(c),0,0,0)
#define SMSCALE 0.18033688011112042f  /* (1/sqrt(64)) * log2(e) */

__device__ __forceinline__ u16 f2bf(float f) {
  union { float f; uint32_t u; } c; c.f = f;
  uint32_t u = c.u;
  uint32_t r = (u + 0x7fffu + ((u >> 16) & 1u)) >> 16;
  return (u16)r;
}

__device__ __forceinline__ void async16(const void* g, void* l) {
  __builtin_amdgcn_global_load_lds((const __attribute__((address_space(1))) void*)g,
                                   (__attribute__((address_space(3))) void*)l,
                                   16, 0, 0);
}

// ---------------- convert x (fp32 -> bf16) ----------------
__global__ __launch_bounds__(256) void k_convert_x(const float4* __restrict__ x,
                                                   u16* __restrict__ xb) {
  int i = blockIdx.x * 256 + threadIdx.x;   // exactly 8192*1024/4 threads
  float4 v = x[i];
  u16x4 o;
  o.x = f2bf(v.x); o.y = f2bf(v.y); o.z = f2bf(v.z); o.w = f2bf(v.w);
  *(u16x4*)(xb + (size_t)i * 4) = o;
}

// ---------------- transpose W (fp32 [k][n] -> bf16 [n][k]) ----------------
__global__ __launch_bounds__(256) void k_transpose_w(const float* __restrict__ src,
                                                     u16* __restrict__ dst) {
  __shared__ float tile[64][65];
  const int bx = blockIdx.x * 64;  // k base
  const int by = blockIdx.y * 64;  // n base
  const int t = threadIdx.x;
  const int tc = (t & 15) * 4;
  const int tr = t >> 4;
  #pragma unroll
  for (int p = 0; p < 4; ++p) {
    int r = tr + p * 16;
    float4 v = *(const float4*)(src + (size_t)(bx + r) * 1024 + by + tc);
    tile[r][tc + 0] = v.x; tile[r][tc + 1] = v.y;
    tile[r][tc + 2] = v.z; tile[r][tc + 3] = v.w;
  }
  __syncthreads();
  #pragma unroll
  for (int p = 0; p < 4; ++p) {
    int r = tr + p * 16;  // n offset within tile
    u16x4 o;
    o.x = f2bf(tile[tc + 0][r]);
    o.y = f2bf(tile[tc + 1][r]);
    o.z = f2bf(tile[tc + 2][r]);
    o.w = f2bf(tile[tc + 3][r]);
    *(u16x4*)(dst + (size_t)(by + r) * 1024 + bx + tc) = o;
  }
}

// ---------------- shared 128x128 GEMM core (A[M][1024] @ Bt[N][1024]^T) ----------------
__device__ __forceinline__ void gemm_core(const u16* __restrict__ A, const u16* __restrict__ Bt,
                                          u16* As, u16* Bs, int m0, int n0, f32x4 acc[4][4]) {
  const int t = threadIdx.x;
  const int lane = t & 63, wv = t >> 6;
  const int lm = lane & 15, quad = lane >> 4;
  const int wr = wv >> 1, wc = wv & 1;
  for (int k0 = 0; k0 < 1024; k0 += 32) {
    #pragma unroll
    for (int it = 0; it < 2; ++it) {
      int chunk = it * 256 + t;          // 512 chunks of 16B per 128x32 tile
      int r = chunk >> 2, c8 = (chunk & 3) * 8;
      u16* ldsA = As + (size_t)(it * 256 + wv * 64) * 8;  // wave-uniform base
      u16* ldsB = Bs + (size_t)(it * 256 + wv * 64) * 8;
      async16(A  + (size_t)(m0 + r) * 1024 + k0 + c8, ldsA);
      async16(Bt + (size_t)(n0 + r) * 1024 + k0 + c8, ldsB);
    }
    __syncthreads();
    frag8 a[4], b[4];
    #pragma unroll
    for (int i = 0; i < 4; ++i) a[i] = *(const frag8*)(As + (wr * 64 + i * 16 + lm) * 32 + quad * 8);
    #pragma unroll
    for (int j = 0; j < 4; ++j) b[j] = *(const frag8*)(Bs + (wc * 64 + j * 16 + lm) * 32 + quad * 8);
    #pragma unroll
    for (int i = 0; i < 4; ++i)
      #pragma unroll
      for (int j = 0; j < 4; ++j)
        acc[i][j] = MFMA_BF16(a[i], b[j], acc[i][j]);
    __syncthreads();
  }
}

// ---------------- QKV projection GEMM ----------------
__global__ __launch_bounds__(256) void k_gemm_qkv(const u16* __restrict__ xb,
    const u16* __restrict__ Wqt, const u16* __restrict__ Wkt, const u16* __restrict__ Wvt,
    u16* __restrict__ Qg, u16* __restrict__ Kg, u16* __restrict__ Vtg) {
  __shared__ __attribute__((aligned(16))) u16 As[128 * 32];
  __shared__ __attribute__((aligned(16))) u16 Bs[128 * 32];
  const int z = blockIdx.z;
  const u16* Bt = (z == 0) ? Wqt : (z == 1) ? Wkt : Wvt;
  const int m0 = blockIdx.x * 128, n0 = blockIdx.y * 128;
  f32x4 acc[4][4] = {};
  gemm_core(xb, Bt, As, Bs, m0, n0, acc);
  const int t = threadIdx.x, lane = t & 63, wv = t >> 6;
  const int lm = lane & 15, quad = lane >> 4;
  const int wr = wv >> 1, wc = wv & 1;
  #pragma unroll
  for (int i = 0; i < 4; ++i)
    #pragma unroll
    for (int j = 0; j < 4; ++j) {
      const int col = n0 + wc * 64 + j * 16 + lm;
      const int h = col >> 6, d = col & 63;
      #pragma unroll
      for (int reg = 0; reg < 4; ++reg) {
        const int row = m0 + wr * 64 + i * 16 + quad * 4 + reg;  // token id 0..8191
        const int bb = row >> 11, nn = row & 2047;
        const u16 v = f2bf(acc[i][j][reg]);
        if (z == 0)      Qg [(((size_t)bb * 16 + h) * 2048 + nn) * 64 + d] = v;
        else if (z == 1) Kg [(((size_t)bb * 16 + h) * 2048 + nn) * 64 + d] = v;
        else             Vtg[(((size_t)bb * 16 + h) * 64 + d) * 2048 + nn] = v;  // V transposed
      }
    }
}

// ---------------- flash attention (causal), one (bh, 64-q-tile) per block ----------------
__global__ __launch_bounds__(256) void k_attn(const u16* __restrict__ Qg, const u16* __restrict__ Kg,
                                              const u16* __restrict__ Vtg, u16* __restrict__ ctx) {
  __shared__ __attribute__((aligned(16))) u16 Qs[64 * 64];
  __shared__ __attribute__((aligned(16))) u16 Ks[64 * 64];
  __shared__ __attribute__((aligned(16))) u16 Vts[64 * 64];   // [d][key]
  __shared__ __attribute__((aligned(16))) u16 Ps[4 * 16 * 64];
  const int qt = blockIdx.x;   // 0..31
  const int bh = blockIdx.y;   // 0..63
  const int t = threadIdx.x, lane = t & 63, wv = t >> 6;
  const int lm = lane & 15, quad = lane >> 4;

  #pragma unroll
  for (int it = 0; it < 2; ++it) {
    int chunk = it * 256 + t;
    int r = chunk >> 3, c8 = (chunk & 7) * 8;
    async16(Qg + ((size_t)bh * 2048 + qt * 64 + r) * 64 + c8, Qs + (it * 256 + wv * 64) * 8);
  }
  __syncthreads();
  frag8 aq[2];
  aq[0] = *(const frag8*)(Qs + (wv * 16 + lm) * 64 + quad * 8);
  aq[1] = *(const frag8*)(Qs + (wv * 16 + lm) * 64 + 32 + quad * 8);

  float m_run[4], l_run[4];
  f32x4 o[4] = {};
  #pragma unroll
  for (int r = 0; r < 4; ++r) { m_run[r] = -__builtin_inff(); l_run[r] = 0.f; }
  const int qrow0 = qt * 64 + wv * 16 + quad * 4;

  for (int kt0 = 0; kt0 <= qt; ++kt0) {
    #pragma unroll
    for (int it = 0; it < 2; ++it) {
      int chunk = it * 256 + t;
      int r = chunk >> 3, c8 = (chunk & 7) * 8;
      async16(Kg  + ((size_t)bh * 2048 + kt0 * 64 + r) * 64 + c8, Ks  + (it * 256 + wv * 64) * 8);
      async16(Vtg + ((size_t)bh * 64 + r) * 2048 + kt0 * 64 + c8,  Vts + (it * 256 + wv * 64) * 8);
    }
    __syncthreads();

    f32x4 s[4];
    #pragma unroll
    for (int kt = 0; kt < 4; ++kt) {
      f32x4 z = {0.f, 0.f, 0.f, 0.f};
      #pragma unroll
      for (int ds = 0; ds < 2; ++ds) {
        frag8 bk = *(const frag8*)(Ks + (kt * 16 + lm) * 64 + ds * 32 + quad * 8);
        z = MFMA_BF16(aq[ds], bk, z);
      }
      s[kt] = z;
    }

    float mt[4];
    #pragma unroll
    for (int r = 0; r < 4; ++r) mt[r] = -__builtin_inff();
    #pragma unroll
    for (int kt = 0; kt < 4; ++kt) {
      const int col = kt0 * 64 + kt * 16 + lm;
      #pragma unroll
      for (int r = 0; r < 4; ++r) {
        float v = s[kt][r];
        if (col > qrow0 + r) v = -__builtin_inff();
        s[kt][r] = v;
        mt[r] = fmaxf(mt[r], v);
      }
    }
    #pragma unroll
    for (int off = 1; off < 16; off <<= 1)
      #pragma unroll
      for (int r = 0; r < 4; ++r)
        mt[r] = fmaxf(mt[r], __shfl_xor(mt[r], off));

    float alpha[4];
    #pragma unroll
    for (int r = 0; r < 4; ++r) {
      float mn = fmaxf(m_run[r], mt[r]);
      alpha[r] = exp2f((m_run[r] - mn) * SMSCALE);
      m_run[r] = mn;
    }

    float rs[4] = {0.f, 0.f, 0.f, 0.f};
    #pragma unroll
    for (int kt = 0; kt < 4; ++kt)
      #pragma unroll
      for (int r = 0; r < 4; ++r) {
        float p = exp2f((s[kt][r] - m_run[r]) * SMSCALE);
        s[kt][r] = p;
        rs[r] += p;
      }
    #pragma unroll
    for (int off = 1; off < 16; off <<= 1)
      #pragma unroll
      for (int r = 0; r < 4; ++r)
        rs[r] += __shfl_xor(rs[r], off);
    #pragma unroll
    for (int r = 0; r < 4; ++r) l_run[r] = l_run[r] * alpha[r] + rs[r];
    #pragma unroll
    for (int dt = 0; dt < 4; ++dt)
      #pragma unroll
      for (int r = 0; r < 4; ++r)
        o[dt][r] *= alpha[r];

    // P: C-layout -> LDS -> A-layout
    #pragma unroll
    for (int kt = 0; kt < 4; ++kt)
      #pragma unroll
      for (int r = 0; r < 4; ++r)
        Ps[wv * 1024 + (quad * 4 + r) * 64 + kt * 16 + lm] = f2bf(s[kt][r]);
    __syncthreads();

    #pragma unroll
    for (int dt = 0; dt < 4; ++dt) {
      #pragma unroll
      for (int ks = 0; ks < 2; ++ks) {
        frag8 ap = *(const frag8*)(Ps + wv * 1024 + lm * 64 + ks * 32 + quad * 8);
        frag8 bv = *(const frag8*)(Vts + (dt * 16 + lm) * 64 + ks * 32 + quad * 8);
        o[dt] = MFMA_BF16(ap, bv, o[dt]);
      }
    }
    __syncthreads();
  }

  const int b = bh >> 4, h = bh & 15;
  #pragma unroll
  for (int dt = 0; dt < 4; ++dt)
    #pragma unroll
    for (int r = 0; r < 4; ++r) {
      float val = o[dt][r] / l_run[r];
      int row = qrow0 + r;
      ctx[((size_t)b * 2048 + row) * 1024 + h * 64 + dt * 16 + lm] = f2bf(val);
    }
}

// ---------------- output projection GEMM (+bias, fp32 out) ----------------
__global__ __launch_bounds__(256) void k_gemm_out(const u16* __restrict__ ctx,
    const u16* __restrict__ Wot, const float* __restrict__ bo, float* __restrict__ out) {
  __shared__ __attribute__((aligned(16))) u16 As[128 * 32];
  __shared__ __attribute__((aligned(16))) u16 Bs[128 * 32];
  const int m0 = blockIdx.x * 128, n0 = blockIdx.y * 128;
  f32x4 acc[4][4] = {};
  gemm_core(ctx, Wot, As, Bs, m0, n0, acc);
  const int t = threadIdx.x, lane = t & 63, wv = t >> 6;
  const int lm = lane & 15, quad = lane >> 4;
  const int wr = wv >> 1, wc = wv & 1;
  #pragma unroll
  for (int i = 0; i < 4; ++i)
    #pragma unroll
    for (int j = 0; j < 4; ++j) {
      const int col = n0 + wc * 64 + j * 16 + lm;
      const float bias = bo[col];
      #pragma unroll
      for (int reg = 0; reg < 4; ++reg) {
        const int row = m0 + wr * 64 + i * 16 + quad * 4 + reg;
        out[(size_t)row * 1024 + col] = acc[i][j][reg] + bias;
      }
    }
}

extern "C" void kernel_launch(void* const* d_in, const int* in_sizes, int n_in,
                              void* d_out, int out_size, void* d_ws, size_t ws_size,
                              hipStream_t stream) {
  const float* x  = (const float*)d_in[0];
  const float* Wq = (const float*)d_in[1];
  const float* Wk = (const float*)d_in[2];
  const float* Wv = (const float*)d_in[3];
  const float* Wo = (const float*)d_in[4];
  const float* bo = (const float*)d_in[5];
  float* out = (float*)d_out;
  char* ws = (char*)d_ws;

  u16* xb   = (u16*)(ws);                          // 16 MB
  u16* Wqt  = (u16*)(ws + ((size_t)16 << 20));     //  2 MB
  u16* Wkt  = (u16*)(ws + ((size_t)18 << 20));
  u16* Wvt  = (u16*)(ws + ((size_t)20 << 20));
  u16* Wot  = (u16*)(ws + ((size_t)22 << 20));
  u16* Qg   = (u16*)(ws + ((size_t)24 << 20));     // 16 MB [b,h,n,64]
  u16* Kg   = (u16*)(ws + ((size_t)40 << 20));     // 16 MB [b,h,n,64]
  u16* Vtg  = (u16*)(ws + ((size_t)56 << 20));     // 16 MB [b,h,64,n]
  u16* ctxb = (u16*)(ws + ((size_t)72 << 20));     // 16 MB [b*n, 1024]

  k_convert_x<<<8192, 256, 0, stream>>>((const float4*)x, xb);
  k_transpose_w<<<dim3(16, 16), 256, 0, stream>>>(Wq, Wqt);
  k_transpose_w<<<dim3(16, 16), 256, 0, stream>>>(Wk, Wkt);
  k_transpose_w<<<dim3(16, 16), 256, 0, stream>>>(Wv, Wvt);
  k_transpose_w<<<dim3(16, 16), 256, 0, stream>>>(Wo, Wot);
  k_gemm_qkv<<<dim3(64, 8, 3), 256, 0, stream>>>(xb, Wqt, Wkt, Wvt, Qg, Kg, Vtg);
  k_attn<<<dim3(32, 64), 256, 0, stream>>>(Qg, Kg, Vtg, ctxb);
  k_gemm_out<<<dim3(64, 8), 256, 0, stream>>>(ctxb, Wot, bo, out);
}

// Round 2
// 282.968 us; speedup vs baseline: 1.8122x; 1.8122x over previous
//
#include <hip/hip_runtime.h>
#include <stdint.h>

typedef unsigned short u16;
typedef __attribute__((ext_vector_type(8))) short frag8;   // 8 bf16 in 4 VGPRs
typedef __attribute__((ext_vector_type(4))) float f32x4;
typedef __attribute__((ext_vector_type(4))) unsigned short u16x4;

#define MFMA_BF16(a,b,c) __builtin_amdgcn_mfma_f32_16x16x32_bf16((a),(b),(c),0,0,0)
#define SMSCALE 0.18033688011112042f  /* (1/sqrt(64)) * log2(e) */

__device__ __forceinline__ u16 f2bf(float f) {
  union { float f; uint32_t u; } c; c.f = f;
  uint32_t u = c.u;
  uint32_t r = (u + 0x7fffu + ((u >> 16) & 1u)) >> 16;
  return (u16)r;
}

// pack two floats' bf16 (round-half-up) into one u32: low=a, high=b
__device__ __forceinline__ uint32_t pack_bf16(float a, float b) {
  uint32_t au = __float_as_uint(a) + 0x8000u;
  uint32_t bu = __float_as_uint(b) + 0x8000u;
  return __builtin_amdgcn_perm(bu, au, 0x07060302u);  // [a.b2,a.b3,b.b2,b.b3]
}

__device__ __forceinline__ void async16(const void* g, void* l) {
  __builtin_amdgcn_global_load_lds((const __attribute__((address_space(1))) void*)g,
                                   (__attribute__((address_space(3))) void*)l,
                                   16, 0, 0);
}

// ---------------- convert x (fp32 -> bf16) ----------------
__global__ __launch_bounds__(256) void k_convert_x(const float4* __restrict__ x,
                                                   u16* __restrict__ xb) {
  int i = blockIdx.x * 256 + threadIdx.x;
  float4 v = x[i];
  u16x4 o;
  o.x = f2bf(v.x); o.y = f2bf(v.y); o.z = f2bf(v.z); o.w = f2bf(v.w);
  *(u16x4*)(xb + (size_t)i * 4) = o;
}

// ---------------- transpose W (fp32 [k][n] -> bf16 [n][k]) ----------------
__global__ __launch_bounds__(256) void k_transpose_w(const float* __restrict__ src,
                                                     u16* __restrict__ dst) {
  __shared__ float tile[64][65];
  const int bx = blockIdx.x * 64;  // k base
  const int by = blockIdx.y * 64;  // n base
  const int t = threadIdx.x;
  const int tc = (t & 15) * 4;
  const int tr = t >> 4;
  #pragma unroll
  for (int p = 0; p < 4; ++p) {
    int r = tr + p * 16;
    float4 v = *(const float4*)(src + (size_t)(bx + r) * 1024 + by + tc);
    tile[r][tc + 0] = v.x; tile[r][tc + 1] = v.y;
    tile[r][tc + 2] = v.z; tile[r][tc + 3] = v.w;
  }
  __syncthreads();
  #pragma unroll
  for (int p = 0; p < 4; ++p) {
    int r = tr + p * 16;
    u16x4 o;
    o.x = f2bf(tile[tc + 0][r]);
    o.y = f2bf(tile[tc + 1][r]);
    o.z = f2bf(tile[tc + 2][r]);
    o.w = f2bf(tile[tc + 3][r]);
    *(u16x4*)(dst + (size_t)(by + r) * 1024 + bx + tc) = o;
  }
}

// ---------------- shared 128x128 GEMM core (A[M][1024] @ Bt[N][1024]^T) ----------------
__device__ __forceinline__ void gemm_core(const u16* __restrict__ A, const u16* __restrict__ Bt,
                                          u16* As, u16* Bs, int m0, int n0, f32x4 acc[4][4]) {
  const int t = threadIdx.x;
  const int lane = t & 63, wv = t >> 6;
  const int lm = lane & 15, quad = lane >> 4;
  const int wr = wv >> 1, wc = wv & 1;
  for (int k0 = 0; k0 < 1024; k0 += 32) {
    #pragma unroll
    for (int it = 0; it < 2; ++it) {
      int chunk = it * 256 + t;
      int r = chunk >> 2, c8 = (chunk & 3) * 8;
      u16* ldsA = As + (size_t)(it * 256 + wv * 64) * 8;
      u16* ldsB = Bs + (size_t)(it * 256 + wv * 64) * 8;
      async16(A  + (size_t)(m0 + r) * 1024 + k0 + c8, ldsA);
      async16(Bt + (size_t)(n0 + r) * 1024 + k0 + c8, ldsB);
    }
    __syncthreads();
    frag8 a[4], b[4];
    #pragma unroll
    for (int i = 0; i < 4; ++i) a[i] = *(const frag8*)(As + (wr * 64 + i * 16 + lm) * 32 + quad * 8);
    #pragma unroll
    for (int j = 0; j < 4; ++j) b[j] = *(const frag8*)(Bs + (wc * 64 + j * 16 + lm) * 32 + quad * 8);
    #pragma unroll
    for (int i = 0; i < 4; ++i)
      #pragma unroll
      for (int j = 0; j < 4; ++j)
        acc[i][j] = MFMA_BF16(a[i], b[j], acc[i][j]);
    __syncthreads();
  }
}

// ---------------- QKV projection GEMM ----------------
__global__ __launch_bounds__(256) void k_gemm_qkv(const u16* __restrict__ xb,
    const u16* __restrict__ Wqt, const u16* __restrict__ Wkt, const u16* __restrict__ Wvt,
    u16* __restrict__ Qg, u16* __restrict__ Kg, u16* __restrict__ Vg) {
  __shared__ __attribute__((aligned(16))) u16 As[128 * 32];
  __shared__ __attribute__((aligned(16))) u16 Bs[128 * 32];
  const int z = blockIdx.z;
  const u16* Bt = (z == 0) ? Wqt : (z == 1) ? Wkt : Wvt;
  u16* tgt = (z == 0) ? Qg : (z == 1) ? Kg : Vg;
  const int m0 = blockIdx.x * 128, n0 = blockIdx.y * 128;
  f32x4 acc[4][4] = {};
  gemm_core(xb, Bt, As, Bs, m0, n0, acc);
  const int t = threadIdx.x, lane = t & 63, wv = t >> 6;
  const int lm = lane & 15, quad = lane >> 4;
  const int wr = wv >> 1, wc = wv & 1;
  #pragma unroll
  for (int i = 0; i < 4; ++i)
    #pragma unroll
    for (int j = 0; j < 4; ++j) {
      const int col = n0 + wc * 64 + j * 16 + lm;
      const int h = col >> 6, d = col & 63;
      #pragma unroll
      for (int reg = 0; reg < 4; ++reg) {
        const int row = m0 + wr * 64 + i * 16 + quad * 4 + reg;  // token id
        const int bb = row >> 11, nn = row & 2047;
        tgt[(((size_t)bb * 16 + h) * 2048 + nn) * 64 + d] = f2bf(acc[i][j][reg]);
      }
    }
}

// ---------------- V transpose: [bh][n][64] -> [bh][64][n] ----------------
__global__ __launch_bounds__(256) void k_transpose_v(const u16* __restrict__ Vg,
                                                     u16* __restrict__ Vtg) {
  __shared__ u16 tile[64][72];
  const int kt = blockIdx.x;   // key tile 0..31
  const int bh = blockIdx.y;
  const int t = threadIdx.x;
  #pragma unroll
  for (int it = 0; it < 2; ++it) {
    int chunk = it * 256 + t;
    int r = chunk >> 3, c = (chunk & 7) * 8;
    *(frag8*)(&tile[r][c]) = *(const frag8*)(Vg + ((size_t)bh * 2048 + kt * 64 + r) * 64 + c);
  }
  __syncthreads();
  #pragma unroll
  for (int it = 0; it < 2; ++it) {
    int chunk = it * 256 + t;
    int dr = chunk >> 3, kc = (chunk & 7) * 8;
    frag8 vv;
    #pragma unroll
    for (int j = 0; j < 8; ++j) vv[j] = (short)tile[kc + j][dr];
    *(frag8*)(Vtg + ((size_t)bh * 64 + dr) * 2048 + kt * 64 + kc) = vv;
  }
}

// ---------------- flash attention (causal), paired q-tiles, S^T formulation ----------------
__global__ __launch_bounds__(256, 5) void k_attn(const u16* __restrict__ Qg,
                                                 const u16* __restrict__ Kg,
                                                 const u16* __restrict__ Vtg,
                                                 u16* __restrict__ ctx) {
  __shared__ __attribute__((aligned(16))) u16 Ks[64 * 64];    // swizzled
  __shared__ __attribute__((aligned(16))) u16 Vts[64 * 64];   // [d][key], swizzled
  __shared__ __attribute__((aligned(16))) u16 Ps[4 * 16 * 72];
  const int pair = blockIdx.x;   // 0..15
  const int bh = blockIdx.y;     // 0..63
  const int t = threadIdx.x, lane = t & 63, wv = t >> 6;
  const int lm = lane & 15, quad = lane >> 4;
  const int b = bh >> 4, h = bh & 15;
  u16* const PsW = Ps + wv * (16 * 72);

  #pragma unroll
  for (int phase = 0; phase < 2; ++phase) {
    const int qt = phase ? (31 - pair) : pair;

    // Q frags straight from global (A of Q^T usage is B operand: lane lm = q row)
    frag8 aq[2];
    {
      const u16* qp = Qg + ((size_t)bh * 2048 + qt * 64 + wv * 16 + lm) * 64 + quad * 8;
      aq[0] = *(const frag8*)(qp);
      aq[1] = *(const frag8*)(qp + 32);
    }
    float m_run = -3.0e38f, l_run = 0.f;
    f32x4 o[4] = {};

    for (int kt0 = 0; kt0 <= qt; ++kt0) {
      // stage K and V^T tiles (xor-swizzled at the global side)
      #pragma unroll
      for (int it = 0; it < 2; ++it) {
        int chunk = it * 256 + t;
        int r = chunk >> 3, c = chunk & 7;
        int sc = (c ^ (r & 7)) * 8;
        u16* dK = Ks  + (size_t)(it * 256 + wv * 64) * 8;
        u16* dV = Vts + (size_t)(it * 256 + wv * 64) * 8;
        async16(Kg  + ((size_t)bh * 2048 + kt0 * 64 + r) * 64 + sc, dK);
        async16(Vtg + ((size_t)bh * 64 + r) * 2048 + kt0 * 64 + sc, dV);
      }
      __syncthreads();

      // S^T = K · Q^T : D[key][q]; row=quad*4+reg=key, col=lm=q
      f32x4 s[4];
      #pragma unroll
      for (int kt = 0; kt < 4; ++kt) {
        f32x4 z = {0.f, 0.f, 0.f, 0.f};
        #pragma unroll
        for (int dd = 0; dd < 2; ++dd) {
          frag8 ak = *(const frag8*)(Ks + (kt * 16 + lm) * 64 + (((dd * 4 + quad) ^ (lm & 7)) * 8));
          z = MFMA_BF16(ak, aq[dd], z);
        }
        s[kt] = z;
      }
      if (kt0 == qt) {  // diagonal tile mask (wave-uniform branch)
        #pragma unroll
        for (int kt = 0; kt < 4; ++kt)
          #pragma unroll
          for (int rg = 0; rg < 4; ++rg)
            if (kt * 16 + quad * 4 + rg > wv * 16 + lm) s[kt][rg] = -3.0e38f;
      }

      // per-lane (q = lm) online softmax
      float mt = s[0][0];
      #pragma unroll
      for (int kt = 0; kt < 4; ++kt)
        #pragma unroll
        for (int rg = 0; rg < 4; ++rg) mt = fmaxf(mt, s[kt][rg]);
      mt = fmaxf(mt, __shfl_xor(mt, 16));
      mt = fmaxf(mt, __shfl_xor(mt, 32));
      float mn = fmaxf(m_run, mt);
      float alpha = exp2f((m_run - mn) * SMSCALE);
      m_run = mn;
      const float msc = mn * SMSCALE;

      float rs = 0.f;
      uint32_t pk[4][2];
      #pragma unroll
      for (int kt = 0; kt < 4; ++kt) {
        float p0 = exp2f(fmaf(s[kt][0], SMSCALE, -msc));
        float p1 = exp2f(fmaf(s[kt][1], SMSCALE, -msc));
        float p2 = exp2f(fmaf(s[kt][2], SMSCALE, -msc));
        float p3 = exp2f(fmaf(s[kt][3], SMSCALE, -msc));
        rs += (p0 + p1) + (p2 + p3);
        pk[kt][0] = pack_bf16(p0, p1);
        pk[kt][1] = pack_bf16(p2, p3);
      }
      rs += __shfl_xor(rs, 16);
      rs += __shfl_xor(rs, 32);
      l_run = l_run * alpha + rs;
      #pragma unroll
      for (int dt = 0; dt < 4; ++dt) o[dt] *= alpha;

      // P[q=lm][key] rows (pad 72) — per-wave region, lgkm-ordered, NO barrier
      #pragma unroll
      for (int kt = 0; kt < 4; ++kt) {
        *(uint32_t*)(PsW + lm * 72 + kt * 16 + quad * 4)     = pk[kt][0];
        *(uint32_t*)(PsW + lm * 72 + kt * 16 + quad * 4 + 2) = pk[kt][1];
      }

      // O^T += V^T · P^T : A = V^T rows (d), B = P rows (q)
      #pragma unroll
      for (int ks = 0; ks < 2; ++ks) {
        frag8 bp = *(const frag8*)(PsW + lm * 72 + ks * 32 + quad * 8);
        #pragma unroll
        for (int dt = 0; dt < 4; ++dt) {
          frag8 av = *(const frag8*)(Vts + (dt * 16 + lm) * 64 + (((ks * 4 + quad) ^ (lm & 7)) * 8));
          o[dt] = MFMA_BF16(av, bp, o[dt]);
        }
      }
      __syncthreads();
    }

    // epilogue: normalize, transpose O^T -> [q][d] through Ps, coalesced 16B stores
    const float inv = 1.0f / l_run;
    #pragma unroll
    for (int dt = 0; dt < 4; ++dt) {
      *(uint32_t*)(PsW + lm * 72 + dt * 16 + quad * 4)     = pack_bf16(o[dt][0] * inv, o[dt][1] * inv);
      *(uint32_t*)(PsW + lm * 72 + dt * 16 + quad * 4 + 2) = pack_bf16(o[dt][2] * inv, o[dt][3] * inv);
    }
    const int rr = lane >> 2, cc = (lane & 3) * 8;
    const size_t row = (size_t)b * 2048 + qt * 64 + wv * 16 + rr;
    #pragma unroll
    for (int half = 0; half < 2; ++half) {
      frag8 vo = *(const frag8*)(PsW + rr * 72 + cc + half * 32);
      *(frag8*)(ctx + row * 1024 + h * 64 + cc + half * 32) = vo;
    }
  }
}

// ---------------- output projection GEMM (+bias, fp32 out) ----------------
__global__ __launch_bounds__(256) void k_gemm_out(const u16* __restrict__ ctx,
    const u16* __restrict__ Wot, const float* __restrict__ bo, float* __restrict__ out) {
  __shared__ __attribute__((aligned(16))) u16 As[128 * 32];
  __shared__ __attribute__((aligned(16))) u16 Bs[128 * 32];
  const int m0 = blockIdx.x * 128, n0 = blockIdx.y * 128;
  f32x4 acc[4][4] = {};
  gemm_core(ctx, Wot, As, Bs, m0, n0, acc);
  const int t = threadIdx.x, lane = t & 63, wv = t >> 6;
  const int lm = lane & 15, quad = lane >> 4;
  const int wr = wv >> 1, wc = wv & 1;
  #pragma unroll
  for (int i = 0; i < 4; ++i)
    #pragma unroll
    for (int j = 0; j < 4; ++j) {
      const int col = n0 + wc * 64 + j * 16 + lm;
      const float bias = bo[col];
      #pragma unroll
      for (int reg = 0; reg < 4; ++reg) {
        const int row = m0 + wr * 64 + i * 16 + quad * 4 + reg;
        out[(size_t)row * 1024 + col] = acc[i][j][reg] + bias;
      }
    }
}

extern "C" void kernel_launch(void* const* d_in, const int* in_sizes, int n_in,
                              void* d_out, int out_size, void* d_ws, size_t ws_size,
                              hipStream_t stream) {
  const float* x  = (const float*)d_in[0];
  const float* Wq = (const float*)d_in[1];
  const float* Wk = (const float*)d_in[2];
  const float* Wv = (const float*)d_in[3];
  const float* Wo = (const float*)d_in[4];
  const float* bo = (const float*)d_in[5];
  float* out = (float*)d_out;
  char* ws = (char*)d_ws;

  u16* xb   = (u16*)(ws);                          // 16 MB
  u16* Wqt  = (u16*)(ws + ((size_t)16 << 20));     //  2 MB each
  u16* Wkt  = (u16*)(ws + ((size_t)18 << 20));
  u16* Wvt  = (u16*)(ws + ((size_t)20 << 20));
  u16* Wot  = (u16*)(ws + ((size_t)22 << 20));
  u16* Qg   = (u16*)(ws + ((size_t)24 << 20));     // 16 MB [b,h,n,64]
  u16* Kg   = (u16*)(ws + ((size_t)40 << 20));     // 16 MB [b,h,n,64]
  u16* Vtg  = (u16*)(ws + ((size_t)56 << 20));     // 16 MB [b,h,64,n]
  u16* ctxb = (u16*)(ws + ((size_t)72 << 20));     // 16 MB; doubles as Vg before k_attn

  u16* Vg = ctxb;  // V in [b,h,n,64] lives here until transposed; dead once k_attn runs

  k_convert_x<<<8192, 256, 0, stream>>>((const float4*)x, xb);
  k_transpose_w<<<dim3(16, 16), 256, 0, stream>>>(Wq, Wqt);
  k_transpose_w<<<dim3(16, 16), 256, 0, stream>>>(Wk, Wkt);
  k_transpose_w<<<dim3(16, 16), 256, 0, stream>>>(Wv, Wvt);
  k_transpose_w<<<dim3(16, 16), 256, 0, stream>>>(Wo, Wot);
  k_gemm_qkv<<<dim3(64, 8, 3), 256, 0, stream>>>(xb, Wqt, Wkt, Wvt, Qg, Kg, Vg);
  k_transpose_v<<<dim3(32, 64), 256, 0, stream>>>(Vg, Vtg);
  k_attn<<<dim3(16, 64), 256, 0, stream>>>(Qg, Kg, Vtg, ctxb);
  k_gemm_out<<<dim3(64, 8), 256, 0, stream>>>(ctxb, Wot, bo, out);
}